// Round 10
// baseline (123.006 us; speedup 1.0000x reference)
//
#include <hip/hip_runtime.h>
#include <math.h>

// NeRF renderer: 16384 rays; 64 coarse + 64 fine samples; HIDDEN=64.
// One wave per ray, 4 waves per 256-thread block, wave-private LDS slices,
// no block barriers. h_j(z) = relu(A_j + z*B_j) affine-in-z trick.
// MLP multiply-accumulates use v_pk_fma_f32 (2 hidden units / instr);
// ReLU is component-wise v_max_f32 (gfx950 has NO v_pk_max_f32).

#define EXP2F(x) __builtin_amdgcn_exp2f(x)
#define LOG2F(x) __builtin_amdgcn_logf(x)
#define RCPF(x)  __builtin_amdgcn_rcpf(x)
#define WSYNC()  __builtin_amdgcn_wave_barrier()

typedef float f32x2 __attribute__((ext_vector_type(2)));

__device__ __forceinline__ f32x2 pk_fma(f32x2 a, f32x2 b, f32x2 c) {
    f32x2 d;
    asm("v_pk_fma_f32 %0, %1, %2, %3" : "=v"(d) : "v"(a), "v"(b), "v"(c));
    return d;
}
__device__ __forceinline__ f32x2 pk_relu(f32x2 a) {
    f32x2 d;
    d.x = fmaxf(a.x, 0.0f);
    d.y = fmaxf(a.y, 0.0f);
    return d;
}

__device__ __forceinline__ float fast_exp(float x)   { return EXP2F(x * 1.44269504088896340736f); }
__device__ __forceinline__ float fast_sigmoid(float x) { return RCPF(1.0f + EXP2F(-x * 1.44269504088896340736f)); }
__device__ __forceinline__ float fast_softplus(float x) {
    float y = EXP2F(-fabsf(x) * 1.44269504088896340736f);
    return fmaxf(x, 0.0f) + 0.6931471805599453f * LOG2F(1.0f + y);
}

struct __align__(16) RayLds {
    float dA[64];      // density A
    float dB[64];      // density B
    float dw[64];      // w_sigma
    float cA[64];      // color A
    float cB[64];      // color B
    float cwr[64];     // Wc2[:,0]
    float cwg[64];     // Wc2[:,1]
    float cwb[64];     // Wc2[:,2]
    float z[64];       // coarse z (sorted)
    float nz[64];      // fine z (sorted)
    float2 cb[64];     // {cdf, z_mid}; cb[63].x ~= 1.0 sentinel
    float2 zs[128];    // merged {z, sigma}
};  // 4096 B per wave

// count over sorted arr[64]
__device__ __forceinline__ int count_lt(const float* __restrict__ arr, float key) {
    int c = 0;
    #pragma unroll
    for (int s = 32; s >= 1; s >>= 1)
        c += (arr[c + s - 1] < key) ? s : 0;
    c += (arr[c] < key) ? 1 : 0;
    return c;
}
__device__ __forceinline__ int count_le(const float* __restrict__ arr, float key) {
    int c = 0;
    #pragma unroll
    for (int s = 32; s >= 1; s >>= 1)
        c += (arr[c + s - 1] <= key) ? s : 0;
    c += (arr[c] <= key) ? 1 : 0;
    return c;
}

__device__ __forceinline__ float density_eval(float zv, const RayLds& R, float bsig) {
    const f32x2* A2 = (const f32x2*)R.dA;
    const f32x2* B2 = (const f32x2*)R.dB;
    const f32x2* W2 = (const f32x2*)R.dw;
    const f32x2 z2 = {zv, zv};
    const f32x2 zero2 = {0.0f, 0.0f};
    f32x2 a0 = zero2, a1 = zero2, a2 = zero2, a3 = zero2;
    #pragma unroll
    for (int g = 0; g < 8; ++g) {
        a0 = pk_fma(pk_relu(pk_fma(z2, B2[4*g+0], A2[4*g+0])), W2[4*g+0], a0);
        a1 = pk_fma(pk_relu(pk_fma(z2, B2[4*g+1], A2[4*g+1])), W2[4*g+1], a1);
        a2 = pk_fma(pk_relu(pk_fma(z2, B2[4*g+2], A2[4*g+2])), W2[4*g+2], a2);
        a3 = pk_fma(pk_relu(pk_fma(z2, B2[4*g+3], A2[4*g+3])), W2[4*g+3], a3);
    }
    float s = ((a0.x + a0.y) + (a1.x + a1.y)) + ((a2.x + a2.y) + (a3.x + a3.y));
    return fast_softplus(s + bsig);
}

__global__ __launch_bounds__(256) void nerf_render_kernel(
    const float* __restrict__ rays_o, const float* __restrict__ rays_d,
    const float* __restrict__ W1, const float* __restrict__ b1,
    const float* __restrict__ w_sigma, const float* __restrict__ b_sigma,
    const float* __restrict__ Wc1, const float* __restrict__ bc1,
    const float* __restrict__ Wc2, const float* __restrict__ bc2,
    float* __restrict__ out, int nrays)
{
    __shared__ RayLds L[4];
    const int wave = threadIdx.x >> 6;
    const int lane = threadIdx.x & 63;
    int ray = blockIdx.x * 4 + wave;
    const bool valid = ray < nrays;
    if (!valid) ray = 0;
    RayLds& R = L[wave];

    const float ox = rays_o[ray * 3 + 0], oy = rays_o[ray * 3 + 1], oz = rays_o[ray * 3 + 2];
    const float dx = rays_d[ray * 3 + 0], dy = rays_d[ray * 3 + 1], dz = rays_d[ray * 3 + 2];
    const float bsig = b_sigma[0];
    const float bc2r = bc2[0], bc2g = bc2[1], bc2b = bc2[2];

    // ---- per-ray affine tables, SoA (lane j = hidden unit j) ----
    {
        const int j = lane;
        float w0 = W1[j], w1 = W1[64 + j], w2 = W1[128 + j];
        R.dA[j] = fmaf(ox, w0, fmaf(oy, w1, fmaf(oz, w2, b1[j])));
        R.dB[j] = fmaf(dx, w0, fmaf(dy, w1, dz * w2));
        R.dw[j] = w_sigma[j];

        float c0 = Wc1[j], c1 = Wc1[64 + j], c2 = Wc1[128 + j];
        float c3 = Wc1[192 + j], c4 = Wc1[256 + j], c5 = Wc1[320 + j];
        R.cA[j] = fmaf(ox, c0, fmaf(oy, c1, fmaf(oz, c2,
                  fmaf(dx, c3, fmaf(dy, c4, fmaf(dz, c5, bc1[j]))))));
        R.cB[j] = fmaf(dx, c0, fmaf(dy, c1, dz * c2));
        R.cwr[j] = Wc2[3 * j + 0];
        R.cwg[j] = Wc2[3 * j + 1];
        R.cwb[j] = Wc2[3 * j + 2];
    }

    // ---- near/far vs cube [-1,1]^3 ----
    float ivx = RCPF(dx + 1e-15f), ivy = RCPF(dy + 1e-15f), ivz = RCPF(dz + 1e-15f);
    float tax = (-1.0f - ox) * ivx, tbx = (1.0f - ox) * ivx;
    float tay = (-1.0f - oy) * ivy, tby = (1.0f - oy) * ivy;
    float taz = (-1.0f - oz) * ivz, tbz = (1.0f - oz) * ivz;
    float nearv = fmaxf(fmaxf(fminf(tax, tbx), fminf(tay, tby)), fminf(taz, tbz));
    float farv  = fminf(fminf(fmaxf(tax, tbx), fmaxf(tay, tby)), fmaxf(taz, tbz));
    if (farv < nearv) { nearv = 1e9f; farv = 1e9f; }
    nearv = fmaxf(nearv, 0.5f);
    const float sample_dist = (farv - nearv) * (1.0f / 64.0f);
    const float step = (farv - nearv) * (1.0f / 63.0f);

    WSYNC();   // tables visible within wave (DS ops wave-ordered)

    // ---- coarse pass ----
    const float z = fmaf((float)lane, step, nearv);
    const float sig = density_eval(z, R, bsig);
    R.z[lane] = z;

    float delta = (lane < 63) ? step : sample_dist;
    float e = fast_exp(-delta * sig);
    float alpha = 1.0f - e;
    float T = e + 1e-15f;

    float pincl = T;
    #pragma unroll
    for (int off = 1; off < 64; off <<= 1) {
        float v = __shfl_up(pincl, off);
        if (lane >= off) pincl *= v;
    }
    float pexcl = __shfl_up(pincl, 1);
    if (lane == 0) pexcl = 1.0f;
    const float wgt = alpha * pexcl;

    // ---- pdf/cdf over weights[1..62] ----
    float val = (lane >= 1 && lane <= 62) ? (wgt + 1e-5f) : 0.0f;
    float sincl = val;
    #pragma unroll
    for (int off = 1; off < 64; off <<= 1) {
        float v = __shfl_up(sincl, off);
        if (lane >= off) sincl += v;
    }
    const float rws = RCPF(__shfl(sincl, 63));
    R.cb[lane] = make_float2(sincl * rws, fmaf(0.5f, step, z));   // {cdf, z_mid}
    WSYNC();

    // ---- inverse-CDF sampling, u_k = (k+0.5)/64, searchsorted-right ----
    const float u = ((float)lane + 0.5f) * (1.0f / 64.0f);
    int ind = 0;
    {
        const float2* cb = R.cb;
        #pragma unroll
        for (int s = 32; s >= 1; s >>= 1)
            ind += (cb[ind + s - 1].x <= u) ? s : 0;
        ind += (cb[ind].x <= u) ? 1 : 0;
    }
    int below = max(ind - 1, 0);
    int above = min(ind, 62);
    float2 lo = R.cb[below];
    float2 hi = R.cb[above];
    float denom = hi.x - lo.x;
    if (denom < 1e-5f) denom = 1.0f;
    float t = (u - lo.x) * RCPF(denom);
    const float nz = fmaf(t, hi.y - lo.y, lo.y);

    const float nsig = density_eval(nz, R, bsig);
    R.nz[lane] = nz;
    WSYNC();

    // ---- stable merge via binary ranks (both arrays sorted) ----
    int posO = lane + count_lt(R.nz, z);
    int posN = lane + count_le(R.z, nz);
    R.zs[posO] = make_float2(z, sig);
    R.zs[posN] = make_float2(nz, nsig);
    WSYNC();

    // ---- final compositing: 2 samples per lane ----
    float4 q = ((const float4*)R.zs)[lane];         // {za, sa, zb, sb}
    float za = q.x, sa = q.y, zb = q.z, sb = q.w;
    float zc = __shfl_down(za, 1);                  // zall[2*lane+2]
    float d0 = zb - za;
    float d1 = (lane < 63) ? (zc - zb) : sample_dist;
    float ea = fast_exp(-d0 * sa), eb = fast_exp(-d1 * sb);
    float a0 = 1.0f - ea, a1 = 1.0f - eb;
    float T0 = ea + 1e-15f, T1 = eb + 1e-15f;

    float ppin = T0 * T1;
    #pragma unroll
    for (int off = 1; off < 64; off <<= 1) {
        float v = __shfl_up(ppin, off);
        if (lane >= off) ppin *= v;
    }
    const float prodAll = __shfl(ppin, 63);   // Π T over all 128 = 1 - weights_sum
    float pex = __shfl_up(ppin, 1);
    if (lane == 0) pex = 1.0f;
    float w0 = a0 * pex;
    float w1 = a1 * pex * T0;

    // ---- color MLP, both samples, packed over unit pairs ----
    const f32x2* A2  = (const f32x2*)R.cA;
    const f32x2* B2  = (const f32x2*)R.cB;
    const f32x2* WR2 = (const f32x2*)R.cwr;
    const f32x2* WG2 = (const f32x2*)R.cwg;
    const f32x2* WB2 = (const f32x2*)R.cwb;
    const f32x2 zero2 = {0.0f, 0.0f};
    const f32x2 za2 = {za, za}, zb2 = {zb, zb};
    f32x2 ar0 = zero2, ag0 = zero2, ab0 = zero2;
    f32x2 ar1 = zero2, ag1 = zero2, ab1 = zero2;
    #pragma unroll
    for (int i = 0; i < 32; ++i) {
        f32x2 a = A2[i], b = B2[i];
        f32x2 wr = WR2[i], wg = WG2[i], wb = WB2[i];
        f32x2 h0 = pk_relu(pk_fma(za2, b, a));
        f32x2 h1 = pk_relu(pk_fma(zb2, b, a));
        ar0 = pk_fma(h0, wr, ar0); ag0 = pk_fma(h0, wg, ag0); ab0 = pk_fma(h0, wb, ab0);
        ar1 = pk_fma(h1, wr, ar1); ag1 = pk_fma(h1, wg, ag1); ab1 = pk_fma(h1, wb, ab1);
    }
    float r0 = fast_sigmoid(ar0.x + ar0.y + bc2r);
    float g0 = fast_sigmoid(ag0.x + ag0.y + bc2g);
    float c0 = fast_sigmoid(ab0.x + ab0.y + bc2b);
    float r1 = fast_sigmoid(ar1.x + ar1.y + bc2r);
    float g1 = fast_sigmoid(ag1.x + ag1.y + bc2g);
    float c1 = fast_sigmoid(ab1.x + ab1.y + bc2b);

    float accR = w0 * r0 + w1 * r1;
    float accG = w0 * g0 + w1 * g1;
    float accB = w0 * c0 + w1 * c1;
    #pragma unroll
    for (int off = 32; off > 0; off >>= 1) {
        accR += __shfl_xor(accR, off);
        accG += __shfl_xor(accG, off);
        accB += __shfl_xor(accB, off);
    }
    if (lane == 0 && valid) {
        // 1 - weights_sum == prod of all T (telescoping; eps error ~1e-13)
        out[ray * 3 + 0] = accR + prodAll;
        out[ray * 3 + 1] = accG + prodAll;
        out[ray * 3 + 2] = accB + prodAll;
    }
}

extern "C" void kernel_launch(void* const* d_in, const int* in_sizes, int n_in,
                              void* d_out, int out_size, void* d_ws, size_t ws_size,
                              hipStream_t stream) {
    const float* rays_o  = (const float*)d_in[0];
    const float* rays_d  = (const float*)d_in[1];
    const float* W1      = (const float*)d_in[2];
    const float* b1      = (const float*)d_in[3];
    const float* w_sigma = (const float*)d_in[4];
    const float* b_sigma = (const float*)d_in[5];
    const float* Wc1     = (const float*)d_in[6];
    const float* bc1     = (const float*)d_in[7];
    const float* Wc2     = (const float*)d_in[8];
    const float* bc2     = (const float*)d_in[9];
    float* out = (float*)d_out;

    int nrays = in_sizes[0] / 3;
    int blocks = (nrays + 3) / 4;
    nerf_render_kernel<<<blocks, 256, 0, stream>>>(
        rays_o, rays_d, W1, b1, w_sigma, b_sigma, Wc1, bc1, Wc2, bc2, out, nrays);
}

// Round 11
// 107.023 us; speedup vs baseline: 1.1493x; 1.1493x over previous
//
#include <hip/hip_runtime.h>
#include <math.h>

// NeRF renderer: 16384 rays; 64 coarse + 64 fine samples; HIDDEN=64.
// One wave per ray, 4 waves per 256-thread block, wave-private LDS slices,
// no block barriers. h_j(z) = relu(A_j + z*B_j) affine-in-z trick.
// Tables read as b128 (float4) LDS broadcasts (round-6's measured-good DS
// schedule); compute uses v_pk_fma_f32 on the float4's two f32x2 halves
// (round-10's measured VALU reduction). ReLU = component v_max_f32
// (gfx950 has no v_pk_max_f32).

#define EXP2F(x) __builtin_amdgcn_exp2f(x)
#define LOG2F(x) __builtin_amdgcn_logf(x)
#define RCPF(x)  __builtin_amdgcn_rcpf(x)
#define WSYNC()  __builtin_amdgcn_wave_barrier()

typedef float f32x2 __attribute__((ext_vector_type(2)));

__device__ __forceinline__ f32x2 pk_fma(f32x2 a, f32x2 b, f32x2 c) {
    f32x2 d;
    asm("v_pk_fma_f32 %0, %1, %2, %3" : "=v"(d) : "v"(a), "v"(b), "v"(c));
    return d;
}
__device__ __forceinline__ f32x2 pk_relu(f32x2 a) {
    f32x2 d;
    d.x = fmaxf(a.x, 0.0f);
    d.y = fmaxf(a.y, 0.0f);
    return d;
}

union F4 { float4 v; f32x2 h[2]; };

__device__ __forceinline__ float fast_exp(float x)   { return EXP2F(x * 1.44269504088896340736f); }
__device__ __forceinline__ float fast_sigmoid(float x) { return RCPF(1.0f + EXP2F(-x * 1.44269504088896340736f)); }
__device__ __forceinline__ float fast_softplus(float x) {
    float y = EXP2F(-fabsf(x) * 1.44269504088896340736f);
    return fmaxf(x, 0.0f) + 0.6931471805599453f * LOG2F(1.0f + y);
}

struct __align__(16) RayLds {
    float dA[64];      // density A
    float dB[64];      // density B
    float dw[64];      // w_sigma
    float cA[64];      // color A
    float cB[64];      // color B
    float cwr[64];     // Wc2[:,0]
    float cwg[64];     // Wc2[:,1]
    float cwb[64];     // Wc2[:,2]
    float z[64];       // coarse z (sorted)
    float nz[64];      // fine z (sorted)
    float2 cb[64];     // {cdf, z_mid}; cb[63].x ~= 1.0 sentinel
    float2 zs[128];    // merged {z, sigma}
};  // 4096 B per wave

// count over sorted arr[64]
__device__ __forceinline__ int count_lt(const float* __restrict__ arr, float key) {
    int c = 0;
    #pragma unroll
    for (int s = 32; s >= 1; s >>= 1)
        c += (arr[c + s - 1] < key) ? s : 0;
    c += (arr[c] < key) ? 1 : 0;
    return c;
}
__device__ __forceinline__ int count_le(const float* __restrict__ arr, float key) {
    int c = 0;
    #pragma unroll
    for (int s = 32; s >= 1; s >>= 1)
        c += (arr[c + s - 1] <= key) ? s : 0;
    c += (arr[c] <= key) ? 1 : 0;
    return c;
}

__device__ __forceinline__ float density_eval(float zv, const RayLds& R, float bsig) {
    const float4* A4 = (const float4*)R.dA;
    const float4* B4 = (const float4*)R.dB;
    const float4* W4 = (const float4*)R.dw;
    const f32x2 z2 = {zv, zv};
    const f32x2 zero2 = {0.0f, 0.0f};
    f32x2 acc0 = zero2, acc1 = zero2, acc2 = zero2, acc3 = zero2;
    #pragma unroll
    for (int g = 0; g < 16; g += 2) {
        F4 a0, b0, w0, a1, b1, w1;
        a0.v = A4[g];     b0.v = B4[g];     w0.v = W4[g];
        a1.v = A4[g + 1]; b1.v = B4[g + 1]; w1.v = W4[g + 1];
        acc0 = pk_fma(pk_relu(pk_fma(z2, b0.h[0], a0.h[0])), w0.h[0], acc0);
        acc1 = pk_fma(pk_relu(pk_fma(z2, b0.h[1], a0.h[1])), w0.h[1], acc1);
        acc2 = pk_fma(pk_relu(pk_fma(z2, b1.h[0], a1.h[0])), w1.h[0], acc2);
        acc3 = pk_fma(pk_relu(pk_fma(z2, b1.h[1], a1.h[1])), w1.h[1], acc3);
    }
    float s = ((acc0.x + acc0.y) + (acc1.x + acc1.y))
            + ((acc2.x + acc2.y) + (acc3.x + acc3.y));
    return fast_softplus(s + bsig);
}

__global__ __launch_bounds__(256) void nerf_render_kernel(
    const float* __restrict__ rays_o, const float* __restrict__ rays_d,
    const float* __restrict__ W1, const float* __restrict__ b1,
    const float* __restrict__ w_sigma, const float* __restrict__ b_sigma,
    const float* __restrict__ Wc1, const float* __restrict__ bc1,
    const float* __restrict__ Wc2, const float* __restrict__ bc2,
    float* __restrict__ out, int nrays)
{
    __shared__ RayLds L[4];
    const int wave = threadIdx.x >> 6;
    const int lane = threadIdx.x & 63;
    int ray = blockIdx.x * 4 + wave;
    const bool valid = ray < nrays;
    if (!valid) ray = 0;
    RayLds& R = L[wave];

    const float ox = rays_o[ray * 3 + 0], oy = rays_o[ray * 3 + 1], oz = rays_o[ray * 3 + 2];
    const float dx = rays_d[ray * 3 + 0], dy = rays_d[ray * 3 + 1], dz = rays_d[ray * 3 + 2];
    const float bsig = b_sigma[0];
    const float bc2r = bc2[0], bc2g = bc2[1], bc2b = bc2[2];

    // ---- per-ray affine tables, SoA (lane j = hidden unit j) ----
    {
        const int j = lane;
        float w0 = W1[j], w1 = W1[64 + j], w2 = W1[128 + j];
        R.dA[j] = fmaf(ox, w0, fmaf(oy, w1, fmaf(oz, w2, b1[j])));
        R.dB[j] = fmaf(dx, w0, fmaf(dy, w1, dz * w2));
        R.dw[j] = w_sigma[j];

        float c0 = Wc1[j], c1 = Wc1[64 + j], c2 = Wc1[128 + j];
        float c3 = Wc1[192 + j], c4 = Wc1[256 + j], c5 = Wc1[320 + j];
        R.cA[j] = fmaf(ox, c0, fmaf(oy, c1, fmaf(oz, c2,
                  fmaf(dx, c3, fmaf(dy, c4, fmaf(dz, c5, bc1[j]))))));
        R.cB[j] = fmaf(dx, c0, fmaf(dy, c1, dz * c2));
        R.cwr[j] = Wc2[3 * j + 0];
        R.cwg[j] = Wc2[3 * j + 1];
        R.cwb[j] = Wc2[3 * j + 2];
    }

    // ---- near/far vs cube [-1,1]^3 ----
    float ivx = RCPF(dx + 1e-15f), ivy = RCPF(dy + 1e-15f), ivz = RCPF(dz + 1e-15f);
    float tax = (-1.0f - ox) * ivx, tbx = (1.0f - ox) * ivx;
    float tay = (-1.0f - oy) * ivy, tby = (1.0f - oy) * ivy;
    float taz = (-1.0f - oz) * ivz, tbz = (1.0f - oz) * ivz;
    float nearv = fmaxf(fmaxf(fminf(tax, tbx), fminf(tay, tby)), fminf(taz, tbz));
    float farv  = fminf(fminf(fmaxf(tax, tbx), fmaxf(tay, tby)), fmaxf(taz, tbz));
    if (farv < nearv) { nearv = 1e9f; farv = 1e9f; }
    nearv = fmaxf(nearv, 0.5f);
    const float sample_dist = (farv - nearv) * (1.0f / 64.0f);
    const float step = (farv - nearv) * (1.0f / 63.0f);

    WSYNC();   // tables visible within wave (DS ops wave-ordered)

    // ---- coarse pass ----
    const float z = fmaf((float)lane, step, nearv);
    const float sig = density_eval(z, R, bsig);
    R.z[lane] = z;

    float delta = (lane < 63) ? step : sample_dist;
    float e = fast_exp(-delta * sig);
    float alpha = 1.0f - e;
    float T = e + 1e-15f;

    float pincl = T;
    #pragma unroll
    for (int off = 1; off < 64; off <<= 1) {
        float v = __shfl_up(pincl, off);
        if (lane >= off) pincl *= v;
    }
    float pexcl = __shfl_up(pincl, 1);
    if (lane == 0) pexcl = 1.0f;
    const float wgt = alpha * pexcl;

    // ---- pdf/cdf over weights[1..62] ----
    float val = (lane >= 1 && lane <= 62) ? (wgt + 1e-5f) : 0.0f;
    float sincl = val;
    #pragma unroll
    for (int off = 1; off < 64; off <<= 1) {
        float v = __shfl_up(sincl, off);
        if (lane >= off) sincl += v;
    }
    const float rws = RCPF(__shfl(sincl, 63));
    R.cb[lane] = make_float2(sincl * rws, fmaf(0.5f, step, z));   // {cdf, z_mid}
    WSYNC();

    // ---- inverse-CDF sampling, u_k = (k+0.5)/64, searchsorted-right ----
    const float u = ((float)lane + 0.5f) * (1.0f / 64.0f);
    int ind = 0;
    {
        const float2* cb = R.cb;
        #pragma unroll
        for (int s = 32; s >= 1; s >>= 1)
            ind += (cb[ind + s - 1].x <= u) ? s : 0;
        ind += (cb[ind].x <= u) ? 1 : 0;
    }
    int below = max(ind - 1, 0);
    int above = min(ind, 62);
    float2 lo = R.cb[below];
    float2 hi = R.cb[above];
    float denom = hi.x - lo.x;
    if (denom < 1e-5f) denom = 1.0f;
    float t = (u - lo.x) * RCPF(denom);
    const float nz = fmaf(t, hi.y - lo.y, lo.y);

    const float nsig = density_eval(nz, R, bsig);
    R.nz[lane] = nz;
    WSYNC();

    // ---- stable merge via binary ranks (both arrays sorted) ----
    int posO = lane + count_lt(R.nz, z);
    int posN = lane + count_le(R.z, nz);
    R.zs[posO] = make_float2(z, sig);
    R.zs[posN] = make_float2(nz, nsig);
    WSYNC();

    // ---- final compositing: 2 samples per lane ----
    float4 q = ((const float4*)R.zs)[lane];         // {za, sa, zb, sb}
    float za = q.x, sa = q.y, zb = q.z, sb = q.w;
    float zc = __shfl_down(za, 1);                  // zall[2*lane+2]
    float d0 = zb - za;
    float d1 = (lane < 63) ? (zc - zb) : sample_dist;
    float ea = fast_exp(-d0 * sa), eb = fast_exp(-d1 * sb);
    float a0 = 1.0f - ea, a1 = 1.0f - eb;
    float T0 = ea + 1e-15f, T1 = eb + 1e-15f;

    float ppin = T0 * T1;
    #pragma unroll
    for (int off = 1; off < 64; off <<= 1) {
        float v = __shfl_up(ppin, off);
        if (lane >= off) ppin *= v;
    }
    const float prodAll = __shfl(ppin, 63);   // Π T over all 128 = 1 - weights_sum
    float pex = __shfl_up(ppin, 1);
    if (lane == 0) pex = 1.0f;
    float w0 = a0 * pex;
    float w1 = a1 * pex * T0;

    // ---- color MLP, both samples; b128 table reads, pk_fma compute ----
    const float4* CA4 = (const float4*)R.cA;
    const float4* CB4 = (const float4*)R.cB;
    const float4* WR4 = (const float4*)R.cwr;
    const float4* WG4 = (const float4*)R.cwg;
    const float4* WB4 = (const float4*)R.cwb;
    const f32x2 zero2 = {0.0f, 0.0f};
    const f32x2 za2 = {za, za}, zb2 = {zb, zb};
    f32x2 ar0 = zero2, ag0 = zero2, ab0 = zero2;
    f32x2 ar1 = zero2, ag1 = zero2, ab1 = zero2;
    #pragma unroll
    for (int g = 0; g < 16; ++g) {
        F4 a, b, wr, wg, wb;
        a.v = CA4[g]; b.v = CB4[g];
        wr.v = WR4[g]; wg.v = WG4[g]; wb.v = WB4[g];
        f32x2 h0l = pk_relu(pk_fma(za2, b.h[0], a.h[0]));
        f32x2 h0h = pk_relu(pk_fma(za2, b.h[1], a.h[1]));
        f32x2 h1l = pk_relu(pk_fma(zb2, b.h[0], a.h[0]));
        f32x2 h1h = pk_relu(pk_fma(zb2, b.h[1], a.h[1]));
        ar0 = pk_fma(h0l, wr.h[0], ar0); ar0 = pk_fma(h0h, wr.h[1], ar0);
        ag0 = pk_fma(h0l, wg.h[0], ag0); ag0 = pk_fma(h0h, wg.h[1], ag0);
        ab0 = pk_fma(h0l, wb.h[0], ab0); ab0 = pk_fma(h0h, wb.h[1], ab0);
        ar1 = pk_fma(h1l, wr.h[0], ar1); ar1 = pk_fma(h1h, wr.h[1], ar1);
        ag1 = pk_fma(h1l, wg.h[0], ag1); ag1 = pk_fma(h1h, wg.h[1], ag1);
        ab1 = pk_fma(h1l, wb.h[0], ab1); ab1 = pk_fma(h1h, wb.h[1], ab1);
    }
    float r0 = fast_sigmoid(ar0.x + ar0.y + bc2r);
    float g0 = fast_sigmoid(ag0.x + ag0.y + bc2g);
    float c0 = fast_sigmoid(ab0.x + ab0.y + bc2b);
    float r1 = fast_sigmoid(ar1.x + ar1.y + bc2r);
    float g1 = fast_sigmoid(ag1.x + ag1.y + bc2g);
    float c1 = fast_sigmoid(ab1.x + ab1.y + bc2b);

    float accR = w0 * r0 + w1 * r1;
    float accG = w0 * g0 + w1 * g1;
    float accB = w0 * c0 + w1 * c1;
    #pragma unroll
    for (int off = 32; off > 0; off >>= 1) {
        accR += __shfl_xor(accR, off);
        accG += __shfl_xor(accG, off);
        accB += __shfl_xor(accB, off);
    }
    if (lane == 0 && valid) {
        // 1 - weights_sum == prod of all T (telescoping; eps error ~1e-13)
        out[ray * 3 + 0] = accR + prodAll;
        out[ray * 3 + 1] = accG + prodAll;
        out[ray * 3 + 2] = accB + prodAll;
    }
}

extern "C" void kernel_launch(void* const* d_in, const int* in_sizes, int n_in,
                              void* d_out, int out_size, void* d_ws, size_t ws_size,
                              hipStream_t stream) {
    const float* rays_o  = (const float*)d_in[0];
    const float* rays_d  = (const float*)d_in[1];
    const float* W1      = (const float*)d_in[2];
    const float* b1      = (const float*)d_in[3];
    const float* w_sigma = (const float*)d_in[4];
    const float* b_sigma = (const float*)d_in[5];
    const float* Wc1     = (const float*)d_in[6];
    const float* bc1     = (const float*)d_in[7];
    const float* Wc2     = (const float*)d_in[8];
    const float* bc2     = (const float*)d_in[9];
    float* out = (float*)d_out;

    int nrays = in_sizes[0] / 3;
    int blocks = (nrays + 3) / 4;
    nerf_render_kernel<<<blocks, 256, 0, stream>>>(
        rays_o, rays_d, W1, b1, w_sigma, b_sigma, Wc1, bc1, Wc2, bc2, out, nrays);
}

// Round 12
// 103.475 us; speedup vs baseline: 1.1888x; 1.0343x over previous
//
#include <hip/hip_runtime.h>
#include <math.h>

// NeRF renderer: 16384 rays; 64 coarse + 64 fine samples; HIDDEN=64.
// One wave per ray, 4 waves per 256-thread block, wave-private LDS slices,
// no block barriers. h_j(z) = relu(A_j + z*B_j) affine-in-z trick.
// SoA tables read as b128 LDS broadcasts; MLP math in <2 x float> via
// __builtin_elementwise_fma -> native v_pk_fma_f32 (NO inline asm, so the
// scheduler can pipeline loads; round-11's asm version stalled on LDS).

#define EXP2F(x) __builtin_amdgcn_exp2f(x)
#define LOG2F(x) __builtin_amdgcn_logf(x)
#define RCPF(x)  __builtin_amdgcn_rcpf(x)
#define WSYNC()  __builtin_amdgcn_wave_barrier()

typedef float f32x2 __attribute__((ext_vector_type(2)));

__device__ __forceinline__ f32x2 pk_fma(f32x2 a, f32x2 b, f32x2 c) {
    return __builtin_elementwise_fma(a, b, c);
}
__device__ __forceinline__ f32x2 pk_relu(f32x2 a) {
    const f32x2 z2 = {0.0f, 0.0f};
    return __builtin_elementwise_max(a, z2);
}

union F4 { float4 v; f32x2 h[2]; };

__device__ __forceinline__ float fast_exp(float x)   { return EXP2F(x * 1.44269504088896340736f); }
__device__ __forceinline__ float fast_sigmoid(float x) { return RCPF(1.0f + EXP2F(-x * 1.44269504088896340736f)); }
__device__ __forceinline__ float fast_softplus(float x) {
    float y = EXP2F(-fabsf(x) * 1.44269504088896340736f);
    return fmaxf(x, 0.0f) + 0.6931471805599453f * LOG2F(1.0f + y);
}

struct __align__(16) RayLds {
    float dA[64];      // density A (SoA)
    float dB[64];      // density B
    float dw[64];      // w_sigma
    float cA[64];      // color A
    float cB[64];      // color B
    float cwr[64];     // Wc2[:,0]
    float cwg[64];     // Wc2[:,1]
    float cwb[64];     // Wc2[:,2]
    float z[64];       // coarse z (sorted)
    float nz[64];      // fine z (sorted)
    float cdf[64];     // cdf[0..62], [63] ~= 1.0 sentinel
    float bins[64];    // z_mid[0..62]
    float zall[128];   // merged z
    float sall[128];   // merged sigma
};  // 4096 B per wave

// count over sorted arr[64]; 7 dependent b32 gathers
__device__ __forceinline__ int count_lt(const float* __restrict__ arr, float key) {
    int c = 0;
    #pragma unroll
    for (int s = 32; s >= 1; s >>= 1)
        c += (arr[c + s - 1] < key) ? s : 0;
    c += (arr[c] < key) ? 1 : 0;
    return c;
}
__device__ __forceinline__ int count_le(const float* __restrict__ arr, float key) {
    int c = 0;
    #pragma unroll
    for (int s = 32; s >= 1; s >>= 1)
        c += (arr[c + s - 1] <= key) ? s : 0;
    c += (arr[c] <= key) ? 1 : 0;
    return c;
}

__device__ __forceinline__ float density_eval(float zv, const RayLds& R, float bsig) {
    const float4* A4 = (const float4*)R.dA;
    const float4* B4 = (const float4*)R.dB;
    const float4* W4 = (const float4*)R.dw;
    const f32x2 z2 = {zv, zv};
    const f32x2 zero2 = {0.0f, 0.0f};
    f32x2 acc0 = zero2, acc1 = zero2, acc2 = zero2, acc3 = zero2;
    #pragma unroll
    for (int g = 0; g < 16; g += 2) {
        F4 a0, b0, w0, a1, b1, w1;
        a0.v = A4[g];     b0.v = B4[g];     w0.v = W4[g];
        a1.v = A4[g + 1]; b1.v = B4[g + 1]; w1.v = W4[g + 1];
        acc0 = pk_fma(pk_relu(pk_fma(z2, b0.h[0], a0.h[0])), w0.h[0], acc0);
        acc1 = pk_fma(pk_relu(pk_fma(z2, b0.h[1], a0.h[1])), w0.h[1], acc1);
        acc2 = pk_fma(pk_relu(pk_fma(z2, b1.h[0], a1.h[0])), w1.h[0], acc2);
        acc3 = pk_fma(pk_relu(pk_fma(z2, b1.h[1], a1.h[1])), w1.h[1], acc3);
    }
    float s = ((acc0.x + acc0.y) + (acc1.x + acc1.y))
            + ((acc2.x + acc2.y) + (acc3.x + acc3.y));
    return fast_softplus(s + bsig);
}

__global__ __launch_bounds__(256) void nerf_render_kernel(
    const float* __restrict__ rays_o, const float* __restrict__ rays_d,
    const float* __restrict__ W1, const float* __restrict__ b1,
    const float* __restrict__ w_sigma, const float* __restrict__ b_sigma,
    const float* __restrict__ Wc1, const float* __restrict__ bc1,
    const float* __restrict__ Wc2, const float* __restrict__ bc2,
    float* __restrict__ out, int nrays)
{
    __shared__ RayLds L[4];
    const int wave = threadIdx.x >> 6;
    const int lane = threadIdx.x & 63;
    int ray = blockIdx.x * 4 + wave;
    const bool valid = ray < nrays;
    if (!valid) ray = 0;
    RayLds& R = L[wave];

    const float ox = rays_o[ray * 3 + 0], oy = rays_o[ray * 3 + 1], oz = rays_o[ray * 3 + 2];
    const float dx = rays_d[ray * 3 + 0], dy = rays_d[ray * 3 + 1], dz = rays_d[ray * 3 + 2];
    const float bsig = b_sigma[0];
    const float bc2r = bc2[0], bc2g = bc2[1], bc2b = bc2[2];

    // ---- per-ray affine tables, SoA (lane j = hidden unit j) ----
    {
        const int j = lane;
        float w0 = W1[j], w1 = W1[64 + j], w2 = W1[128 + j];
        R.dA[j] = fmaf(ox, w0, fmaf(oy, w1, fmaf(oz, w2, b1[j])));
        R.dB[j] = fmaf(dx, w0, fmaf(dy, w1, dz * w2));
        R.dw[j] = w_sigma[j];

        float c0 = Wc1[j], c1 = Wc1[64 + j], c2 = Wc1[128 + j];
        float c3 = Wc1[192 + j], c4 = Wc1[256 + j], c5 = Wc1[320 + j];
        R.cA[j] = fmaf(ox, c0, fmaf(oy, c1, fmaf(oz, c2,
                  fmaf(dx, c3, fmaf(dy, c4, fmaf(dz, c5, bc1[j]))))));
        R.cB[j] = fmaf(dx, c0, fmaf(dy, c1, dz * c2));
        R.cwr[j] = Wc2[3 * j + 0];
        R.cwg[j] = Wc2[3 * j + 1];
        R.cwb[j] = Wc2[3 * j + 2];
    }

    // ---- near/far vs cube [-1,1]^3 ----
    float ivx = RCPF(dx + 1e-15f), ivy = RCPF(dy + 1e-15f), ivz = RCPF(dz + 1e-15f);
    float tax = (-1.0f - ox) * ivx, tbx = (1.0f - ox) * ivx;
    float tay = (-1.0f - oy) * ivy, tby = (1.0f - oy) * ivy;
    float taz = (-1.0f - oz) * ivz, tbz = (1.0f - oz) * ivz;
    float nearv = fmaxf(fmaxf(fminf(tax, tbx), fminf(tay, tby)), fminf(taz, tbz));
    float farv  = fminf(fminf(fmaxf(tax, tbx), fmaxf(tay, tby)), fmaxf(taz, tbz));
    if (farv < nearv) { nearv = 1e9f; farv = 1e9f; }
    nearv = fmaxf(nearv, 0.5f);
    const float sample_dist = (farv - nearv) * (1.0f / 64.0f);
    const float step = (farv - nearv) * (1.0f / 63.0f);

    WSYNC();   // tables visible within wave (DS ops wave-ordered)

    // ---- coarse pass ----
    const float z = fmaf((float)lane, step, nearv);
    const float sig = density_eval(z, R, bsig);
    R.z[lane] = z;

    float delta = (lane < 63) ? step : sample_dist;
    float e = fast_exp(-delta * sig);
    float alpha = 1.0f - e;
    float T = e + 1e-15f;

    float pincl = T;
    #pragma unroll
    for (int off = 1; off < 64; off <<= 1) {
        float v = __shfl_up(pincl, off);
        if (lane >= off) pincl *= v;
    }
    float pexcl = __shfl_up(pincl, 1);
    if (lane == 0) pexcl = 1.0f;
    const float wgt = alpha * pexcl;

    // ---- pdf/cdf over weights[1..62] ----
    float val = (lane >= 1 && lane <= 62) ? (wgt + 1e-5f) : 0.0f;
    float sincl = val;
    #pragma unroll
    for (int off = 1; off < 64; off <<= 1) {
        float v = __shfl_up(sincl, off);
        if (lane >= off) sincl += v;
    }
    const float rws = RCPF(__shfl(sincl, 63));
    R.cdf[lane]  = sincl * rws;          // lane63 ~= 1.0 sentinel (> u_max)
    R.bins[lane] = fmaf(0.5f, step, z);  // z_mid
    WSYNC();

    // ---- inverse-CDF sampling, u_k = (k+0.5)/64, searchsorted-right ----
    const float u = ((float)lane + 0.5f) * (1.0f / 64.0f);
    int ind = count_le(R.cdf, u);
    int below = max(ind - 1, 0);
    int above = min(ind, 62);
    float cdf0 = R.cdf[below], cdf1 = R.cdf[above];
    float bin0 = R.bins[below], bin1 = R.bins[above];
    float denom = cdf1 - cdf0;
    if (denom < 1e-5f) denom = 1.0f;
    float t = (u - cdf0) * RCPF(denom);
    const float nz = fmaf(t, bin1 - bin0, bin0);

    const float nsig = density_eval(nz, R, bsig);
    R.nz[lane] = nz;
    WSYNC();

    // ---- stable merge via binary ranks (both arrays sorted) ----
    int posO = lane + count_lt(R.nz, z);
    int posN = lane + count_le(R.z, nz);
    R.zall[posO] = z;   R.sall[posO] = sig;
    R.zall[posN] = nz;  R.sall[posN] = nsig;
    WSYNC();

    // ---- final compositing: 2 samples per lane ----
    float2 zz = ((const float2*)R.zall)[lane];
    float2 ss = ((const float2*)R.sall)[lane];
    float za = zz.x, zb = zz.y;
    float zc = __shfl_down(za, 1);      // zall[2*lane+2]
    float d0 = zb - za;
    float d1 = (lane < 63) ? (zc - zb) : sample_dist;
    float ea = fast_exp(-d0 * ss.x), eb = fast_exp(-d1 * ss.y);
    float a0 = 1.0f - ea, a1 = 1.0f - eb;
    float T0 = ea + 1e-15f, T1 = eb + 1e-15f;

    float ppin = T0 * T1;
    #pragma unroll
    for (int off = 1; off < 64; off <<= 1) {
        float v = __shfl_up(ppin, off);
        if (lane >= off) ppin *= v;
    }
    const float prodAll = __shfl(ppin, 63);   // Π T over all 128 = 1 - weights_sum
    float pex = __shfl_up(ppin, 1);
    if (lane == 0) pex = 1.0f;
    float w0 = a0 * pex;
    float w1 = a1 * pex * T0;

    // ---- color MLP, both samples; b128 SoA reads, packed math ----
    const float4* CA4 = (const float4*)R.cA;
    const float4* CB4 = (const float4*)R.cB;
    const float4* WR4 = (const float4*)R.cwr;
    const float4* WG4 = (const float4*)R.cwg;
    const float4* WB4 = (const float4*)R.cwb;
    const f32x2 zero2 = {0.0f, 0.0f};
    const f32x2 za2 = {za, za}, zb2 = {zb, zb};
    f32x2 ar0 = zero2, ag0 = zero2, ab0 = zero2;
    f32x2 ar1 = zero2, ag1 = zero2, ab1 = zero2;
    #pragma unroll
    for (int g = 0; g < 16; ++g) {
        F4 a, b, wr, wg, wb;
        a.v = CA4[g]; b.v = CB4[g];
        wr.v = WR4[g]; wg.v = WG4[g]; wb.v = WB4[g];
        f32x2 h0l = pk_relu(pk_fma(za2, b.h[0], a.h[0]));
        f32x2 h0h = pk_relu(pk_fma(za2, b.h[1], a.h[1]));
        f32x2 h1l = pk_relu(pk_fma(zb2, b.h[0], a.h[0]));
        f32x2 h1h = pk_relu(pk_fma(zb2, b.h[1], a.h[1]));
        ar0 = pk_fma(h0l, wr.h[0], ar0); ar0 = pk_fma(h0h, wr.h[1], ar0);
        ag0 = pk_fma(h0l, wg.h[0], ag0); ag0 = pk_fma(h0h, wg.h[1], ag0);
        ab0 = pk_fma(h0l, wb.h[0], ab0); ab0 = pk_fma(h0h, wb.h[1], ab0);
        ar1 = pk_fma(h1l, wr.h[0], ar1); ar1 = pk_fma(h1h, wr.h[1], ar1);
        ag1 = pk_fma(h1l, wg.h[0], ag1); ag1 = pk_fma(h1h, wg.h[1], ag1);
        ab1 = pk_fma(h1l, wb.h[0], ab1); ab1 = pk_fma(h1h, wb.h[1], ab1);
    }
    float r0 = fast_sigmoid(ar0.x + ar0.y + bc2r);
    float g0 = fast_sigmoid(ag0.x + ag0.y + bc2g);
    float c0 = fast_sigmoid(ab0.x + ab0.y + bc2b);
    float r1 = fast_sigmoid(ar1.x + ar1.y + bc2r);
    float g1 = fast_sigmoid(ag1.x + ag1.y + bc2g);
    float c1 = fast_sigmoid(ab1.x + ab1.y + bc2b);

    float accR = w0 * r0 + w1 * r1;
    float accG = w0 * g0 + w1 * g1;
    float accB = w0 * c0 + w1 * c1;
    #pragma unroll
    for (int off = 32; off > 0; off >>= 1) {
        accR += __shfl_xor(accR, off);
        accG += __shfl_xor(accG, off);
        accB += __shfl_xor(accB, off);
    }
    if (lane == 0 && valid) {
        // 1 - weights_sum == prod of all T (telescoping; eps error ~1e-13)
        out[ray * 3 + 0] = accR + prodAll;
        out[ray * 3 + 1] = accG + prodAll;
        out[ray * 3 + 2] = accB + prodAll;
    }
}

extern "C" void kernel_launch(void* const* d_in, const int* in_sizes, int n_in,
                              void* d_out, int out_size, void* d_ws, size_t ws_size,
                              hipStream_t stream) {
    const float* rays_o  = (const float*)d_in[0];
    const float* rays_d  = (const float*)d_in[1];
    const float* W1      = (const float*)d_in[2];
    const float* b1      = (const float*)d_in[3];
    const float* w_sigma = (const float*)d_in[4];
    const float* b_sigma = (const float*)d_in[5];
    const float* Wc1     = (const float*)d_in[6];
    const float* bc1     = (const float*)d_in[7];
    const float* Wc2     = (const float*)d_in[8];
    const float* bc2     = (const float*)d_in[9];
    float* out = (float*)d_out;

    int nrays = in_sizes[0] / 3;
    int blocks = (nrays + 3) / 4;
    nerf_render_kernel<<<blocks, 256, 0, stream>>>(
        rays_o, rays_d, W1, b1, w_sigma, b_sigma, Wc1, bc1, Wc2, bc2, out, nrays);
}

// Round 15
// 101.687 us; speedup vs baseline: 1.2096x; 1.0176x over previous
//
#include <hip/hip_runtime.h>
#include <math.h>

// NeRF renderer: 16384 rays; 64 coarse + 64 fine samples; HIDDEN=64.
// One wave per ray, 4 waves per 256-thread block, wave-private LDS slices,
// no block barriers. h_j(z) = relu(A_j + z*B_j) affine-in-z trick.
// DS-pipe offload: (a) wave scans/reductions via DPP (VALU pipe) instead of
// shfl/ds_bpermute; (b) static weights (w_sigma, Wc2^T) staged to d_ws, read
// at wave-uniform addresses (scalar/VMEM path, not DS).
// Wave64 DPP scan row_masks: bcast15 -> 0xa, bcast31 -> 0xc (0xf would
// double-count row 1 into lanes 32-47).

#define EXP2F(x) __builtin_amdgcn_exp2f(x)
#define LOG2F(x) __builtin_amdgcn_logf(x)
#define RCPF(x)  __builtin_amdgcn_rcpf(x)
#define WSYNC()  __builtin_amdgcn_wave_barrier()

typedef float f32x2 __attribute__((ext_vector_type(2)));

__device__ __forceinline__ f32x2 pk_fma(f32x2 a, f32x2 b, f32x2 c) {
    return __builtin_elementwise_fma(a, b, c);
}
__device__ __forceinline__ f32x2 pk_relu(f32x2 a) {
    const f32x2 z2 = {0.0f, 0.0f};
    return __builtin_elementwise_max(a, z2);
}

union F4 { float4 v; f32x2 h[2]; };

// DPP cross-lane on the VALU pipe. Masked-out / invalid lanes yield `old`
// (the identity), so the combining op leaves them unchanged.
#define DPPF(x, ctrl, old, rmask) \
    __int_as_float(__builtin_amdgcn_update_dpp( \
        __float_as_int(old), __float_as_int(x), (ctrl), (rmask), 0xf, false))

// wave64 inclusive product scan (Hillis-Steele in-row, then row carries)
__device__ __forceinline__ float scan_mul(float x) {
    x *= DPPF(x, 0x111, 1.0f, 0xf);   // row_shr:1
    x *= DPPF(x, 0x112, 1.0f, 0xf);   // row_shr:2
    x *= DPPF(x, 0x114, 1.0f, 0xf);   // row_shr:4
    x *= DPPF(x, 0x118, 1.0f, 0xf);   // row_shr:8
    x *= DPPF(x, 0x142, 1.0f, 0xa);   // row_bcast:15 -> rows 1,3 only
    x *= DPPF(x, 0x143, 1.0f, 0xc);   // row_bcast:31 -> rows 2,3 only
    return x;
}
__device__ __forceinline__ float scan_add(float x) {
    x += DPPF(x, 0x111, 0.0f, 0xf);
    x += DPPF(x, 0x112, 0.0f, 0xf);
    x += DPPF(x, 0x114, 0.0f, 0xf);
    x += DPPF(x, 0x118, 0.0f, 0xf);
    x += DPPF(x, 0x142, 0.0f, 0xa);
    x += DPPF(x, 0x143, 0.0f, 0xc);
    return x;
}
__device__ __forceinline__ float lane63(float x) {
    return __int_as_float(__builtin_amdgcn_readlane(__float_as_int(x), 63));
}

__device__ __forceinline__ float fast_exp(float x)   { return EXP2F(x * 1.44269504088896340736f); }
__device__ __forceinline__ float fast_sigmoid(float x) { return RCPF(1.0f + EXP2F(-x * 1.44269504088896340736f)); }
__device__ __forceinline__ float fast_softplus(float x) {
    float y = EXP2F(-fabsf(x) * 1.44269504088896340736f);
    return fmaxf(x, 0.0f) + 0.6931471805599453f * LOG2F(1.0f + y);
}

struct __align__(16) RayLds {
    float dA[64];      // density A (per-ray)
    float dB[64];      // density B
    float cA[64];      // color A
    float cB[64];      // color B
    float z[64];       // coarse z (sorted)
    float nz[64];      // fine z (sorted)
    float cdf[64];     // cdf[0..62], [63] ~= 1.0 sentinel
    float bins[64];    // z_mid[0..62]
    float zall[128];   // merged z
    float sall[128];   // merged sigma
};  // 3072 B per wave -> 12288 B per block

// count over sorted arr[64]; 7 dependent b32 gathers
__device__ __forceinline__ int count_lt(const float* __restrict__ arr, float key) {
    int c = 0;
    #pragma unroll
    for (int s = 32; s >= 1; s >>= 1)
        c += (arr[c + s - 1] < key) ? s : 0;
    c += (arr[c] < key) ? 1 : 0;
    return c;
}
__device__ __forceinline__ int count_le(const float* __restrict__ arr, float key) {
    int c = 0;
    #pragma unroll
    for (int s = 32; s >= 1; s >>= 1)
        c += (arr[c + s - 1] <= key) ? s : 0;
    c += (arr[c] <= key) ? 1 : 0;
    return c;
}

// density: A,B from LDS (per-ray), w from wT+192 (uniform -> scalar loads)
__device__ __forceinline__ float density_eval(float zv, const RayLds& R,
                                              const float* __restrict__ wT, float bsig) {
    const float4* A4 = (const float4*)R.dA;
    const float4* B4 = (const float4*)R.dB;
    const float4* W4 = (const float4*)(wT + 192);
    const f32x2 z2 = {zv, zv};
    const f32x2 zero2 = {0.0f, 0.0f};
    f32x2 acc0 = zero2, acc1 = zero2, acc2 = zero2, acc3 = zero2;
    #pragma unroll
    for (int g = 0; g < 16; g += 2) {
        F4 a0, b0, w0, a1, b1, w1;
        a0.v = A4[g];     b0.v = B4[g];     w0.v = W4[g];
        a1.v = A4[g + 1]; b1.v = B4[g + 1]; w1.v = W4[g + 1];
        acc0 = pk_fma(pk_relu(pk_fma(z2, b0.h[0], a0.h[0])), w0.h[0], acc0);
        acc1 = pk_fma(pk_relu(pk_fma(z2, b0.h[1], a0.h[1])), w0.h[1], acc1);
        acc2 = pk_fma(pk_relu(pk_fma(z2, b1.h[0], a1.h[0])), w1.h[0], acc2);
        acc3 = pk_fma(pk_relu(pk_fma(z2, b1.h[1], a1.h[1])), w1.h[1], acc3);
    }
    float s = ((acc0.x + acc0.y) + (acc1.x + acc1.y))
            + ((acc2.x + acc2.y) + (acc3.x + acc3.y));
    return fast_softplus(s + bsig);
}

// stage static weights transposed into d_ws (re-done every launch; d_ws is
// re-poisoned by the harness before each timed call)
__global__ void setup_weights(const float* __restrict__ w_sigma,
                              const float* __restrict__ Wc2,
                              float* __restrict__ wT) {
    const int j = threadIdx.x;   // 64 threads
    wT[j]       = Wc2[3 * j + 0];
    wT[64 + j]  = Wc2[3 * j + 1];
    wT[128 + j] = Wc2[3 * j + 2];
    wT[192 + j] = w_sigma[j];
}

__global__ __launch_bounds__(256) void nerf_render_kernel(
    const float* __restrict__ rays_o, const float* __restrict__ rays_d,
    const float* __restrict__ W1, const float* __restrict__ b1,
    const float* __restrict__ b_sigma,
    const float* __restrict__ Wc1, const float* __restrict__ bc1,
    const float* __restrict__ bc2,
    const float* __restrict__ wT,
    float* __restrict__ out, int nrays)
{
    __shared__ RayLds L[4];
    const int wave = threadIdx.x >> 6;
    const int lane = threadIdx.x & 63;
    int ray = blockIdx.x * 4 + wave;
    const bool valid = ray < nrays;
    if (!valid) ray = 0;
    RayLds& R = L[wave];

    const float ox = rays_o[ray * 3 + 0], oy = rays_o[ray * 3 + 1], oz = rays_o[ray * 3 + 2];
    const float dx = rays_d[ray * 3 + 0], dy = rays_d[ray * 3 + 1], dz = rays_d[ray * 3 + 2];
    const float bsig = b_sigma[0];
    const float bc2r = bc2[0], bc2g = bc2[1], bc2b = bc2[2];

    // ---- per-ray affine tables (lane j = hidden unit j) ----
    {
        const int j = lane;
        float w0 = W1[j], w1 = W1[64 + j], w2 = W1[128 + j];
        R.dA[j] = fmaf(ox, w0, fmaf(oy, w1, fmaf(oz, w2, b1[j])));
        R.dB[j] = fmaf(dx, w0, fmaf(dy, w1, dz * w2));

        float c0 = Wc1[j], c1 = Wc1[64 + j], c2 = Wc1[128 + j];
        float c3 = Wc1[192 + j], c4 = Wc1[256 + j], c5 = Wc1[320 + j];
        R.cA[j] = fmaf(ox, c0, fmaf(oy, c1, fmaf(oz, c2,
                  fmaf(dx, c3, fmaf(dy, c4, fmaf(dz, c5, bc1[j]))))));
        R.cB[j] = fmaf(dx, c0, fmaf(dy, c1, dz * c2));
    }

    // ---- near/far vs cube [-1,1]^3 ----
    float ivx = RCPF(dx + 1e-15f), ivy = RCPF(dy + 1e-15f), ivz = RCPF(dz + 1e-15f);
    float tax = (-1.0f - ox) * ivx, tbx = (1.0f - ox) * ivx;
    float tay = (-1.0f - oy) * ivy, tby = (1.0f - oy) * ivy;
    float taz = (-1.0f - oz) * ivz, tbz = (1.0f - oz) * ivz;
    float nearv = fmaxf(fmaxf(fminf(tax, tbx), fminf(tay, tby)), fminf(taz, tbz));
    float farv  = fminf(fminf(fmaxf(tax, tbx), fmaxf(tay, tby)), fmaxf(taz, tbz));
    if (farv < nearv) { nearv = 1e9f; farv = 1e9f; }
    nearv = fmaxf(nearv, 0.5f);
    const float sample_dist = (farv - nearv) * (1.0f / 64.0f);
    const float step = (farv - nearv) * (1.0f / 63.0f);

    WSYNC();   // tables visible within wave (DS ops wave-ordered)

    // ---- coarse pass ----
    const float z = fmaf((float)lane, step, nearv);
    const float sig = density_eval(z, R, wT, bsig);
    R.z[lane] = z;

    float delta = (lane < 63) ? step : sample_dist;
    float e = fast_exp(-delta * sig);
    float alpha = 1.0f - e;
    float T = e + 1e-15f;

    // exclusive product via inclusive DPP scan + rcp (rel err ~1e-6)
    float pincl = scan_mul(T);
    float pexcl = pincl * RCPF(T);
    const float wgt = alpha * pexcl;

    // ---- pdf/cdf over weights[1..62] (DPP add scan) ----
    float val = (lane >= 1 && lane <= 62) ? (wgt + 1e-5f) : 0.0f;
    float sincl = scan_add(val);
    const float rws = RCPF(lane63(sincl));
    R.cdf[lane]  = sincl * rws;          // lane63 ~= 1.0 sentinel (> u_max)
    R.bins[lane] = fmaf(0.5f, step, z);  // z_mid
    WSYNC();

    // ---- inverse-CDF sampling, u_k = (k+0.5)/64, searchsorted-right ----
    const float u = ((float)lane + 0.5f) * (1.0f / 64.0f);
    int ind = count_le(R.cdf, u);
    int below = max(ind - 1, 0);
    int above = min(ind, 62);
    float cdf0 = R.cdf[below], cdf1 = R.cdf[above];
    float bin0 = R.bins[below], bin1 = R.bins[above];
    float denom = cdf1 - cdf0;
    if (denom < 1e-5f) denom = 1.0f;
    float t = (u - cdf0) * RCPF(denom);
    const float nz = fmaf(t, bin1 - bin0, bin0);

    const float nsig = density_eval(nz, R, wT, bsig);
    R.nz[lane] = nz;
    WSYNC();

    // ---- stable merge via binary ranks (both arrays sorted) ----
    int posO = lane + count_lt(R.nz, z);
    int posN = lane + count_le(R.z, nz);
    R.zall[posO] = z;   R.sall[posO] = sig;
    R.zall[posN] = nz;  R.sall[posN] = nsig;
    WSYNC();

    // ---- final compositing: 2 samples per lane ----
    float2 zz = ((const float2*)R.zall)[lane];
    float2 ss = ((const float2*)R.sall)[lane];
    float za = zz.x, zb = zz.y;
    float zc = __shfl_down(za, 1);      // zall[2*lane+2]
    float d0 = zb - za;
    float d1 = (lane < 63) ? (zc - zb) : sample_dist;
    float ea = fast_exp(-d0 * ss.x), eb = fast_exp(-d1 * ss.y);
    float a0 = 1.0f - ea, a1 = 1.0f - eb;
    float T0 = ea + 1e-15f, T1 = eb + 1e-15f;

    float P = T0 * T1;
    float ppin = scan_mul(P);
    const float prodAll = lane63(ppin);  // prod of all T = 1 - weights_sum
    float pex = ppin * RCPF(P);          // exclusive pair prefix
    float w0 = a0 * pex;
    float w1 = a1 * pex * T0;

    // ---- color MLP, both samples; A,B from LDS b128, weights from wT ----
    const float4* CA4 = (const float4*)R.cA;
    const float4* CB4 = (const float4*)R.cB;
    const float4* WR4 = (const float4*)(wT);
    const float4* WG4 = (const float4*)(wT + 64);
    const float4* WB4 = (const float4*)(wT + 128);
    const f32x2 zero2 = {0.0f, 0.0f};
    const f32x2 za2 = {za, za}, zb2 = {zb, zb};
    f32x2 ar0 = zero2, ag0 = zero2, ab0 = zero2;
    f32x2 ar1 = zero2, ag1 = zero2, ab1 = zero2;
    #pragma unroll
    for (int g = 0; g < 16; ++g) {
        F4 a, b, wr, wg, wb;
        a.v = CA4[g]; b.v = CB4[g];
        wr.v = WR4[g]; wg.v = WG4[g]; wb.v = WB4[g];
        f32x2 h0l = pk_relu(pk_fma(za2, b.h[0], a.h[0]));
        f32x2 h0h = pk_relu(pk_fma(za2, b.h[1], a.h[1]));
        f32x2 h1l = pk_relu(pk_fma(zb2, b.h[0], a.h[0]));
        f32x2 h1h = pk_relu(pk_fma(zb2, b.h[1], a.h[1]));
        ar0 = pk_fma(h0l, wr.h[0], ar0); ar0 = pk_fma(h0h, wr.h[1], ar0);
        ag0 = pk_fma(h0l, wg.h[0], ag0); ag0 = pk_fma(h0h, wg.h[1], ag0);
        ab0 = pk_fma(h0l, wb.h[0], ab0); ab0 = pk_fma(h0h, wb.h[1], ab0);
        ar1 = pk_fma(h1l, wr.h[0], ar1); ar1 = pk_fma(h1h, wr.h[1], ar1);
        ag1 = pk_fma(h1l, wg.h[0], ag1); ag1 = pk_fma(h1h, wg.h[1], ag1);
        ab1 = pk_fma(h1l, wb.h[0], ab1); ab1 = pk_fma(h1h, wb.h[1], ab1);
    }
    float r0 = fast_sigmoid(ar0.x + ar0.y + bc2r);
    float g0 = fast_sigmoid(ag0.x + ag0.y + bc2g);
    float c0 = fast_sigmoid(ab0.x + ab0.y + bc2b);
    float r1 = fast_sigmoid(ar1.x + ar1.y + bc2r);
    float g1 = fast_sigmoid(ag1.x + ag1.y + bc2g);
    float c1 = fast_sigmoid(ab1.x + ab1.y + bc2b);

    // output reductions on the VALU pipe (DPP scan + readlane)
    float totR = lane63(scan_add(w0 * r0 + w1 * r1));
    float totG = lane63(scan_add(w0 * g0 + w1 * g1));
    float totB = lane63(scan_add(w0 * c0 + w1 * c1));

    if (lane == 0 && valid) {
        out[ray * 3 + 0] = totR + prodAll;
        out[ray * 3 + 1] = totG + prodAll;
        out[ray * 3 + 2] = totB + prodAll;
    }
}

extern "C" void kernel_launch(void* const* d_in, const int* in_sizes, int n_in,
                              void* d_out, int out_size, void* d_ws, size_t ws_size,
                              hipStream_t stream) {
    const float* rays_o  = (const float*)d_in[0];
    const float* rays_d  = (const float*)d_in[1];
    const float* W1      = (const float*)d_in[2];
    const float* b1      = (const float*)d_in[3];
    const float* w_sigma = (const float*)d_in[4];
    const float* b_sigma = (const float*)d_in[5];
    const float* Wc1     = (const float*)d_in[6];
    const float* bc1     = (const float*)d_in[7];
    const float* Wc2     = (const float*)d_in[8];
    const float* bc2     = (const float*)d_in[9];
    float* out = (float*)d_out;
    float* wT  = (float*)d_ws;   // 256 floats staged

    setup_weights<<<1, 64, 0, stream>>>(w_sigma, Wc2, wT);

    int nrays = in_sizes[0] / 3;
    int blocks = (nrays + 3) / 4;
    nerf_render_kernel<<<blocks, 256, 0, stream>>>(
        rays_o, rays_d, W1, b1, b_sigma, Wc1, bc1, bc2, wT, out, nrays);
}